// Round 7
// baseline (119.441 us; speedup 1.0000x reference)
//
#include <hip/hip_runtime.h>

#define NROWS 16384
#define DDIM  256
#define K1BLK 2048   // 8 blocks/CU -> 32 waves/CU: max latency hiding (R0-proven)
#define RBLK  64     // k2 blocks: 32-row strip reduce + replicated W GEMV

// g = (X W)(X^T (X b)) via u = Xb, v = X^T u, w2 = W v, g = X w2.
// R14: back to 3 dispatches (kernel boundaries are the cheap barrier: R0's
// 3 kernels = ~16us total vs fused 21-27us). Single change vs R0: k1's 524K
// device-scope atomicAdds (~6-7us serialization) -> unique plain stores
// p1[2048][256]; k2 reduces 32-row strips and folds the second reduce level
// into W algebraically: w2 = sum_j W . vpart_j, accumulated with only 16K
// fire-and-forget atomicAdds (poison base -3e-13/elem: validated tolerable).

// ---------------------------------------------------------------------------
// k1: per-row t = x.b (6-step butterfly), vacc += t*x; 2 rows/wave x 4 waves
// x 2048 blocks. LDS-combine 4 wave partials -> ONE plain coalesced store
// per thread into the block's unique partial row. No atomics, no memset.
// ---------------------------------------------------------------------------
__global__ __launch_bounds__(256) void k1_v(const float* __restrict__ X,
                                            const float* __restrict__ b,
                                            float* __restrict__ p1) {
    const int tid  = threadIdx.x;
    const int lane = tid & 63;
    const int wave = tid >> 6;
    const int bid  = blockIdx.x;

    const float4* X4 = (const float4*)X;
    const float4  bf = ((const float4*)b)[lane];

    float4 vacc = make_float4(0.f, 0.f, 0.f, 0.f);
    const int row0 = bid * 8 + wave * 2;
    #pragma unroll
    for (int i = 0; i < 2; ++i) {
        const float4 xv = X4[(row0 + i) * 64 + lane];
        float t = xv.x * bf.x + xv.y * bf.y + xv.z * bf.z + xv.w * bf.w;
        #pragma unroll
        for (int off = 32; off; off >>= 1) t += __shfl_xor(t, off, 64);
        vacc.x += t * xv.x; vacc.y += t * xv.y;
        vacc.z += t * xv.z; vacc.w += t * xv.w;
    }

    __shared__ float sp[4][DDIM];
    ((float4*)sp[wave])[lane] = vacc;
    __syncthreads();
    p1[bid * DDIM + tid] = sp[0][tid] + sp[1][tid] + sp[2][tid] + sp[3][tid];
}

// ---------------------------------------------------------------------------
// k2: 64 blocks. Block j: (1) coalesced float4 strip-reduce of p1 rows
// [32j, 32j+32) (32 KB, L2/L3-hot, plain loads -- kernel boundary already
// made k1's stores visible) -> vpart in LDS; (2) wave-per-row GEMV over ALL
// 256 W rows (64 rows/wave, coalesced float4 row reads + butterfly);
// lane0 atomicAdd into w2[row]: 16K RMWs total, fire-and-forget at kernel
// end. w2 poison base = -3.03e-13/elem: negligible, no memset needed.
// ---------------------------------------------------------------------------
__global__ __launch_bounds__(256) void k2_w2(const float* __restrict__ p1,
                                             const float* __restrict__ W,
                                             float* __restrict__ w2) {
    const int tid  = threadIdx.x;
    const int lane = tid & 63;
    const int wave = tid >> 6;
    const int bid  = blockIdx.x;

    const float4* P4 = (const float4*)p1;
    float4 acc = make_float4(0.f, 0.f, 0.f, 0.f);
    const int rbase = bid * 32 + wave * 8;
    #pragma unroll
    for (int i = 0; i < 8; ++i) {
        const float4 p = P4[(rbase + i) * 64 + lane];
        acc.x += p.x; acc.y += p.y; acc.z += p.z; acc.w += p.w;
    }

    __shared__ __align__(16) float sp[4 * DDIM];
    __shared__ __align__(16) float sv[DDIM];
    ((float4*)&sp[wave * DDIM])[lane] = acc;
    __syncthreads();
    sv[tid] = sp[tid] + sp[DDIM + tid] + sp[2 * DDIM + tid] + sp[3 * DDIM + tid];
    __syncthreads();

    // replicated GEMV: this block contributes W . vpart_j
    const float4* W4  = (const float4*)W;
    const float4  vf  = ((const float4*)sv)[lane];
    #pragma unroll 4
    for (int r = 0; r < 64; ++r) {
        const int row = wave * 64 + r;
        const float4 wv = W4[row * 64 + lane];
        float t = wv.x * vf.x + wv.y * vf.y + wv.z * vf.z + wv.w * vf.w;
        #pragma unroll
        for (int off = 32; off; off >>= 1) t += __shfl_xor(t, off, 64);
        if (lane == 0) atomicAdd(&w2[row], t);
    }
}

// ---------------------------------------------------------------------------
// k3: g = X w2. 2048 blocks, 2 rows/wave. X is L3-warm from k1.
// ---------------------------------------------------------------------------
__global__ __launch_bounds__(256) void k3_g(const float* __restrict__ X,
                                            const float* __restrict__ w2,
                                            float* __restrict__ g) {
    const int tid  = threadIdx.x;
    const int lane = tid & 63;
    const int wave = tid >> 6;

    const float4* X4 = (const float4*)X;
    const float4  wf = ((const float4*)w2)[lane];

    const int row0 = blockIdx.x * 8 + wave * 2;
    #pragma unroll
    for (int i = 0; i < 2; ++i) {
        const float4 xv = X4[(row0 + i) * 64 + lane];
        float t = xv.x * wf.x + xv.y * wf.y + xv.z * wf.z + xv.w * wf.w;
        #pragma unroll
        for (int off = 32; off; off >>= 1) t += __shfl_xor(t, off, 64);
        if (lane == 0) g[row0 + i] = t;
    }
}

extern "C" void kernel_launch(void* const* d_in, const int* in_sizes, int n_in,
                              void* d_out, int out_size, void* d_ws, size_t ws_size,
                              hipStream_t stream) {
    const float* X = (const float*)d_in[0];   // (16384, 256)
    const float* W = (const float*)d_in[1];   // (256, 256)
    const float* b = (const float*)d_in[2];   // (256,)
    float* out = (float*)d_out;               // (16384,)

    float* p1 = (float*)d_ws;                 // 2048*256 floats (2 MB), fully written
    float* w2 = p1 + K1BLK * DDIM;            // 256 floats (poison-tolerant atomicAdd)

    k1_v <<<K1BLK, 256, 0, stream>>>(X, b, p1);
    k2_w2<<<RBLK,  256, 0, stream>>>(p1, W, w2);
    k3_g <<<K1BLK, 256, 0, stream>>>(X, w2, out);
}

// Round 8
// 100.719 us; speedup vs baseline: 1.1859x; 1.1859x over previous
//
#include <hip/hip_runtime.h>

#define NROWS 16384
#define DDIM  256
#define K1BLK 2048   // 8 blocks/CU -> 32 waves/CU: max latency hiding (R0-proven)
#define K2BLK 16     // k2 blocks: 128-row strip reduce + replicated W GEMV each

// g = (X W)(X^T (X b)) via u = Xb, v = X^T u, w2 = W v, g = X w2.
// R15: ZERO atomics. R7 counters: k2 was 53us because 16K SINGLE-LANE
// atomicAdds hit 16 cachelines (1024 packets/line x ~50ns serialized
// cross-XCD ping-pong). Model update: atomic cost = packets-per-line, not
// op count (R0's 524K COALESCED atomics were ~free: 32 packets/line).
// Fix: k2 stages its per-row GEMV results in LDS and plain-stores a unique
// row p2[j][256]; k3 folds w2 = sum_j p2[j] (16 coalesced hot loads,
// hidden at 32 waves/CU). All cross-kernel visibility via kernel
// boundaries -- no atomics, no fences, no memset anywhere.

// ---------------------------------------------------------------------------
// k1: per-row t = x.b (6-step butterfly), vacc += t*x; 2 rows/wave x 4 waves
// x 2048 blocks. LDS-combine 4 wave partials -> ONE plain coalesced store
// per thread into the block's unique partial row.
// ---------------------------------------------------------------------------
__global__ __launch_bounds__(256) void k1_v(const float* __restrict__ X,
                                            const float* __restrict__ b,
                                            float* __restrict__ p1) {
    const int tid  = threadIdx.x;
    const int lane = tid & 63;
    const int wave = tid >> 6;
    const int bid  = blockIdx.x;

    const float4* X4 = (const float4*)X;
    const float4  bf = ((const float4*)b)[lane];

    float4 vacc = make_float4(0.f, 0.f, 0.f, 0.f);
    const int row0 = bid * 8 + wave * 2;
    #pragma unroll
    for (int i = 0; i < 2; ++i) {
        const float4 xv = X4[(row0 + i) * 64 + lane];
        float t = xv.x * bf.x + xv.y * bf.y + xv.z * bf.z + xv.w * bf.w;
        #pragma unroll
        for (int off = 32; off; off >>= 1) t += __shfl_xor(t, off, 64);
        vacc.x += t * xv.x; vacc.y += t * xv.y;
        vacc.z += t * xv.z; vacc.w += t * xv.w;
    }

    __shared__ float sp[4][DDIM];
    ((float4*)sp[wave])[lane] = vacc;
    __syncthreads();
    p1[bid * DDIM + tid] = sp[0][tid] + sp[1][tid] + sp[2][tid] + sp[3][tid];
}

// ---------------------------------------------------------------------------
// k2: 16 blocks. Block j: (1) float4 strip-reduce of p1 rows [128j,128j+128)
// (plain coalesced loads; kernel boundary made k1's stores visible) ->
// vpart_j in LDS; (2) replicated GEMV y_j = W . vpart_j: wave-per-row
// butterfly over all 256 W rows, results staged in LDS sy[256];
// (3) ONE plain coalesced store: p2[j][tid] = sy[tid]. No atomics.
// ---------------------------------------------------------------------------
__global__ __launch_bounds__(256) void k2_w2(const float* __restrict__ p1,
                                             const float* __restrict__ W,
                                             float* __restrict__ p2) {
    const int tid  = threadIdx.x;
    const int lane = tid & 63;
    const int wave = tid >> 6;
    const int bid  = blockIdx.x;

    const float4* P4 = (const float4*)p1;
    float4 acc = make_float4(0.f, 0.f, 0.f, 0.f);
    const int rbase = bid * 128 + wave * 32;
    #pragma unroll 8
    for (int i = 0; i < 32; ++i) {
        const float4 p = P4[(rbase + i) * 64 + lane];
        acc.x += p.x; acc.y += p.y; acc.z += p.z; acc.w += p.w;
    }

    __shared__ __align__(16) float sp[4 * DDIM];
    __shared__ __align__(16) float sv[DDIM];
    __shared__ __align__(16) float sy[DDIM];
    ((float4*)&sp[wave * DDIM])[lane] = acc;
    __syncthreads();
    sv[tid] = sp[tid] + sp[DDIM + tid] + sp[2 * DDIM + tid] + sp[3 * DDIM + tid];
    __syncthreads();

    // replicated GEMV: y_j = W . vpart_j, staged in LDS (no global RMWs)
    const float4* W4 = (const float4*)W;
    const float4  vf = ((const float4*)sv)[lane];
    #pragma unroll 4
    for (int r = 0; r < 64; ++r) {
        const int row = wave * 64 + r;
        const float4 wv = W4[row * 64 + lane];
        float t = wv.x * vf.x + wv.y * vf.y + wv.z * vf.z + wv.w * vf.w;
        #pragma unroll
        for (int off = 32; off; off >>= 1) t += __shfl_xor(t, off, 64);
        if (lane == 0) sy[row] = t;
    }
    __syncthreads();
    p2[bid * DDIM + tid] = sy[tid];   // unique row, plain coalesced store
}

// ---------------------------------------------------------------------------
// k3: fold w2 = sum_j p2[j] (16 coalesced L3-hot loads, latency hidden at
// 32 waves/CU), then g = X w2. 2048 blocks, 2 rows/wave. X L3-warm from k1.
// ---------------------------------------------------------------------------
__global__ __launch_bounds__(256) void k3_g(const float* __restrict__ X,
                                            const float* __restrict__ p2,
                                            float* __restrict__ g) {
    const int tid  = threadIdx.x;
    const int lane = tid & 63;
    const int wave = tid >> 6;

    __shared__ __align__(16) float sv[DDIM];
    float s = 0.f;
    #pragma unroll
    for (int j = 0; j < K2BLK; ++j) s += p2[j * DDIM + tid];
    sv[tid] = s;
    __syncthreads();

    const float4* X4 = (const float4*)X;
    const float4  wf = ((const float4*)sv)[lane];

    const int row0 = blockIdx.x * 8 + wave * 2;
    #pragma unroll
    for (int i = 0; i < 2; ++i) {
        const float4 xv = X4[(row0 + i) * 64 + lane];
        float t = xv.x * wf.x + xv.y * wf.y + xv.z * wf.z + xv.w * wf.w;
        #pragma unroll
        for (int off = 32; off; off >>= 1) t += __shfl_xor(t, off, 64);
        if (lane == 0) g[row0 + i] = t;
    }
}

extern "C" void kernel_launch(void* const* d_in, const int* in_sizes, int n_in,
                              void* d_out, int out_size, void* d_ws, size_t ws_size,
                              hipStream_t stream) {
    const float* X = (const float*)d_in[0];   // (16384, 256)
    const float* W = (const float*)d_in[1];   // (256, 256)
    const float* b = (const float*)d_in[2];   // (256,)
    float* out = (float*)d_out;               // (16384,)

    float* p1 = (float*)d_ws;                 // 2048*256 floats (2 MB), fully written
    float* p2 = p1 + K1BLK * DDIM;            // 16*256 floats, fully written

    k1_v <<<K1BLK, 256, 0, stream>>>(X, b, p1);
    k2_w2<<<K2BLK, 256, 0, stream>>>(p1, W, p2);
    k3_g <<<K1BLK, 256, 0, stream>>>(X, p2, out);
}